// Round 4
// baseline (953.364 us; speedup 1.0000x reference)
//
#include <hip/hip_runtime.h>
#include <math.h>

#define NPTS 4096
#define HALF 2048
#define KNN 16
#define H_DIM 128
#define HID1 64
#define A_DIM 32
#define G_DIM 16

#define LIST_ROWS 16    // per-lane candidate buffer depth; reused for final lists
#define FLUSH_AT 8      // flush when any lane reaches this (7+8=15 <= 16 cap)
#define WARMUP 64       // direct-insert first candidates of each half to seed threshold

__global__ __launch_bounds__(128) void knn_film_mlp_kernel(
    const float* __restrict__ pos,   // (B, N, 3)
    const float* __restrict__ goal,  // (B, 16)
    const float* __restrict__ W1,    // (6, 64)
    const float* __restrict__ b1,    // (64)
    const float* __restrict__ W2,    // (64, 128)
    const float* __restrict__ b2,    // (128)
    const float* __restrict__ Wg,    // (16, 128)
    const float* __restrict__ bg,    // (128)
    const float* __restrict__ Wb,    // (16, 128)
    const float* __restrict__ bb,    // (128)
    const float* __restrict__ Wa,    // (128, 32)
    const float* __restrict__ ba,    // (32)
    float* __restrict__ out)         // (B, N, 32)
{
    __shared__ float4 sp[NPTS];                    // x, y, z, |p|^2  (64 KB)
    __shared__ float          bufd[LIST_ROWS][128]; // 8 KB: scan buffer, then sorted d2 lists
    __shared__ unsigned short bufi[LIST_ROWS][128]; // 4 KB: indices (fit in 16 bits)
    __shared__ float gam[H_DIM], bet[H_DIM];        // 1 KB

    const int tid  = threadIdx.x;
    const int lane = tid & 63;
    const int wid  = tid >> 6;                     // 2 waves: candidate-half owners
    const int b     = blockIdx.x >> 6;             // 64 chunks of 64 queries per batch
    const int chunk = blockIdx.x & 63;
    const int q     = chunk * 64 + lane;           // both waves own the same 64 queries

    // ---- stage this batch's points into LDS as float4(x,y,z,sq) ----
    // sq matches numpy's ((x*x + y*y) + z*z) with per-op rounding (no fma).
    const float* pb = pos + (size_t)b * NPTS * 3;
    for (int j = tid; j < NPTS; j += 128) {
        float x = pb[j * 3 + 0];
        float y = pb[j * 3 + 1];
        float z = pb[j * 3 + 2];
        float sq = __fadd_rn(__fadd_rn(__fmul_rn(x, x), __fmul_rn(y, y)),
                             __fmul_rn(z, z));
        sp[j] = make_float4(x, y, z, sq);
    }

    // ---- FiLM gamma/beta for this batch (one c per thread) ----
    {
        const float* gl = goal + b * G_DIM;
        for (int c = tid; c < H_DIM; c += 128) {
            float sg = bg[c];
            float sb = bb[c];
            #pragma unroll
            for (int g = 0; g < G_DIM; ++g) {
                float gv = gl[g];
                sg = fmaf(gv, Wg[g * H_DIM + c], sg);
                sb = fmaf(gv, Wb[g * H_DIM + c], sb);
            }
            gam[c] = sg;
            bet[c] = sb;
        }
    }
    __syncthreads();

    // ---- kNN scan: wave `wid` scans candidate half [wid*2048, wid*2048+2048) ----
    const float4 me = sp[q];

    float best[KNN];
    int   bidx[KNN];
    #pragma unroll
    for (int k = 0; k < KNN; ++k) { best[k] = 3.4e38f; bidx[k] = 0; }

    // d2 in numpy's exact association: dot=((xx'+yy')+zz'); d2=(sqi+sqj)-2*dot.
    // 2*dot is exact; one rounding on the subtract -> bit-identical to reference.
#define CAND_D2(c)                                                             \
    __fsub_rn(__fadd_rn(me.w, (c).w),                                          \
              __fmul_rn(2.0f,                                                  \
                        __fadd_rn(__fadd_rn(__fmul_rn(me.x, (c).x),            \
                                            __fmul_rn(me.y, (c).y)),           \
                                  __fmul_rn(me.z, (c).z))))

#define INSERT_SORTED(d2v, idxv)                                               \
    do {                                                                       \
        best[KNN - 1] = (d2v);                                                 \
        bidx[KNN - 1] = (idxv);                                                \
        _Pragma("unroll")                                                      \
        for (int k = KNN - 1; k > 0; --k) {                                    \
            bool  sw = best[k] < best[k - 1];                                  \
            float lo = fminf(best[k - 1], best[k]);                            \
            float hi = fmaxf(best[k - 1], best[k]);                            \
            int  ilo = sw ? bidx[k]     : bidx[k - 1];                         \
            int  ihi = sw ? bidx[k - 1] : bidx[k];                             \
            best[k - 1] = lo; best[k] = hi;                                    \
            bidx[k - 1] = ilo; bidx[k] = ihi;                                  \
        }                                                                      \
    } while (0)

    const int jbase = wid * HALF;

    // warmup: branchy direct insert (nearly every wave-iter inserts anyway)
    for (int j = jbase; j < jbase + WARMUP; ++j) {
        float4 c = sp[j];
        float d2 = fmaxf(CAND_D2(c), 0.0f);
        if (d2 < best[KNN - 1]) {            // strict < : lowest-index tie-break
            INSERT_SORTED(d2, j);
        }
    }

    float thr = best[KNN - 1];
    int   cnt = 0;

    // buffered main scan: cheap filter + LDS append; insertion only in flushes
    for (int j0 = jbase + WARMUP; j0 < jbase + HALF; j0 += 8) {
        #pragma unroll
        for (int jj = 0; jj < 8; ++jj) {
            const int j = j0 + jj;
            float4 c = sp[j];
            float d2 = fmaxf(CAND_D2(c), 0.0f);
            if (d2 < thr) {                  // predicated append, ~4 ops
                bufd[cnt][tid] = d2;
                bufi[cnt][tid] = (unsigned short)j;
                cnt++;
            }
        }
        if (__any(cnt >= FLUSH_AT)) {        // per-wave ballot; waves flush independently
            int t = 0;
            while (__any(t < cnt)) {
                float d2  = bufd[t][tid];
                int   idx = bufi[t][tid];
                if ((t < cnt) && (d2 < best[KNN - 1])) {
                    INSERT_SORTED(d2, idx);
                }
                t++;
            }
            cnt = 0;
            thr = best[KNN - 1];
        }
    }
    // final flush
    {
        int t = 0;
        while (__any(t < cnt)) {
            float d2  = bufd[t][tid];
            int   idx = bufi[t][tid];
            if ((t < cnt) && (d2 < best[KNN - 1])) {
                INSERT_SORTED(d2, idx);
            }
            t++;
        }
    }

    // ---- publish both waves' sorted lists to LDS (reuse scan buffers) ----
    #pragma unroll
    for (int k = 0; k < KNN; ++k) {
        bufd[k][tid] = best[k];
        bufi[k][tid] = (unsigned short)bidx[k];
    }
    __syncthreads();

    if (wid == 1) return;                    // wave 1 done; wave 0 merges + MLP

    // ---- stable two-pointer merge: list A (j<2048) beats B on ties ----
    // ia/ib are runtime values used only as LDS offsets (no register-array
    // dynamic indexing -> no scratch).
    int midx[KNN];
    {
        int ia = 0, ib = 0;
        #pragma unroll
        for (int m = 0; m < KNN; ++m) {      // ia,ib <= 15 always (ia+ib==m)
            float da = bufd[ia][lane];
            float db = bufd[ib][64 + lane];
            bool takeB = db < da;            // strict: tie -> A (lower index)
            int ja = bufi[ia][lane];
            int jb = bufi[ib][64 + lane];
            midx[m] = takeB ? jb : ja;
            ia += takeB ? 0 : 1;
            ib += takeB ? 1 : 0;
        }
    }

    // ---- neighbor mean offset (merged order == ascending distance == ref) ----
    float sx = 0.0f, sy = 0.0f, sz = 0.0f;
    #pragma unroll
    for (int k = 0; k < KNN; ++k) {
        float4 nb = sp[midx[k]];
        sx += nb.x; sy += nb.y; sz += nb.z;
    }
    const float inv = 1.0f / (float)KNN;
    const float lx = sx * inv - me.x;
    const float ly = sy * inv - me.y;
    const float lz = sz * inv - me.z;

    // ---- MLP: h = relu([pos, ctx] @ W1 + b1) ----
    const float x0 = me.x, x1 = me.y, x2 = me.z, x3 = lx, x4 = ly, x5 = lz;
    float h[HID1];
    #pragma unroll
    for (int c = 0; c < HID1; ++c) {
        float a = b1[c];
        a = fmaf(x0, W1[0 * HID1 + c], a);
        a = fmaf(x1, W1[1 * HID1 + c], a);
        a = fmaf(x2, W1[2 * HID1 + c], a);
        a = fmaf(x3, W1[3 * HID1 + c], a);
        a = fmaf(x4, W1[4 * HID1 + c], a);
        a = fmaf(x5, W1[5 * HID1 + c], a);
        h[c] = fmaxf(a, 0.0f);
    }

    // ---- stream hidden-128 through FiLM into the 32-wide affordance acc ----
    float acc[A_DIM];
    #pragma unroll
    for (int a = 0; a < A_DIM; ++a) acc[a] = ba[a];

    for (int c = 0; c < H_DIM; ++c) {
        float s = b2[c];
        #pragma unroll
        for (int k = 0; k < HID1; ++k) s = fmaf(h[k], W2[k * H_DIM + c], s);
        float f = fmaxf(s, 0.0f);
        f = fmaf(gam[c], f, bet[c]);
        const float* wac = Wa + c * A_DIM;
        #pragma unroll
        for (int a = 0; a < A_DIM; ++a) acc[a] = fmaf(f, wac[a], acc[a]);
    }

    // ---- relu + float4 stores ----
    float4* op4 = (float4*)(out + ((size_t)b * NPTS + q) * A_DIM);
    #pragma unroll
    for (int v = 0; v < A_DIM / 4; ++v) {
        float4 o;
        o.x = fmaxf(acc[v * 4 + 0], 0.0f);
        o.y = fmaxf(acc[v * 4 + 1], 0.0f);
        o.z = fmaxf(acc[v * 4 + 2], 0.0f);
        o.w = fmaxf(acc[v * 4 + 3], 0.0f);
        op4[v] = o;
    }
#undef CAND_D2
#undef INSERT_SORTED
}

extern "C" void kernel_launch(void* const* d_in, const int* in_sizes, int n_in,
                              void* d_out, int out_size, void* d_ws, size_t ws_size,
                              hipStream_t stream) {
    const float* pos  = (const float*)d_in[0];
    const float* goal = (const float*)d_in[1];
    const float* W1   = (const float*)d_in[2];
    const float* b1   = (const float*)d_in[3];
    const float* W2   = (const float*)d_in[4];
    const float* b2   = (const float*)d_in[5];
    const float* Wg   = (const float*)d_in[6];
    const float* bg   = (const float*)d_in[7];
    const float* Wb   = (const float*)d_in[8];
    const float* bb   = (const float*)d_in[9];
    const float* Wa   = (const float*)d_in[10];
    const float* ba   = (const float*)d_in[11];
    float* out = (float*)d_out;

    const int B = in_sizes[0] / (NPTS * 3);
    dim3 grid(B * 64);
    dim3 block(128);
    hipLaunchKernelGGL(knn_film_mlp_kernel, grid, block, 0, stream,
                       pos, goal, W1, b1, W2, b2, Wg, bg, Wb, bb, Wa, ba, out);
}

// Round 5
// 371.986 us; speedup vs baseline: 2.5629x; 2.5629x over previous
//
#include <hip/hip_runtime.h>
#include <math.h>

#define NPTS 4096
#define QTR 1024
#define KNN 16
#define H_DIM 128
#define HID1 64
#define A_DIM 32
#define G_DIM 16

#define BUF_ROWS 8      // per-lane candidate buffer depth (cnt <= 7 by construction)
#define FLUSH_AT 4      // flush when any lane reaches this after a 4-group
#define GROUP 4
#define WARMUP 64       // direct-insert first candidates of each quarter to seed thr

typedef unsigned long long u64;

// key = (f32-bits of d2) << 32 | j.  d2 >= 0 -> u64 ascending == (d2 asc, j asc),
// exactly jax.lax.top_k's order (stable, lowest-index tie-break).

// ---- hand-chained swap network: NO loops, NO runtime indices (scratch-proof) ----
#define SWAP_ST(k)                                                         \
    { bool sw_ = best[k] < best[k-1];                                      \
      u64 lo_ = sw_ ? best[k] : best[k-1];                                 \
      u64 hi_ = sw_ ? best[k-1] : best[k];                                 \
      best[k-1] = lo_; best[k] = hi_; }

#define INSERT_KEY(keyv)                                                   \
    { best[15] = (keyv);                                                   \
      SWAP_ST(15) SWAP_ST(14) SWAP_ST(13) SWAP_ST(12) SWAP_ST(11)          \
      SWAP_ST(10) SWAP_ST(9)  SWAP_ST(8)  SWAP_ST(7)  SWAP_ST(6)           \
      SWAP_ST(5)  SWAP_ST(4)  SWAP_ST(3)  SWAP_ST(2)  SWAP_ST(1) }

#define CE(i, j)                                                           \
    { u64 x_ = m[i], y_ = m[j];                                            \
      bool sw_ = y_ < x_;                                                  \
      m[i] = sw_ ? y_ : x_; m[j] = sw_ ? x_ : y_; }

__global__ __launch_bounds__(256, 2) void knn_film_mlp_kernel(
    const float* __restrict__ pos,   // (B, N, 3)
    const float* __restrict__ goal,  // (B, 16)
    const float* __restrict__ W1,    // (6, 64)
    const float* __restrict__ b1,    // (64)
    const float* __restrict__ W2,    // (64, 128)
    const float* __restrict__ b2,    // (128)
    const float* __restrict__ Wg,    // (16, 128)
    const float* __restrict__ bg,    // (128)
    const float* __restrict__ Wb,    // (16, 128)
    const float* __restrict__ bb,    // (128)
    const float* __restrict__ Wa,    // (128, 32)
    const float* __restrict__ ba,    // (32)
    float* __restrict__ out)         // (B, N, 32)
{
    __shared__ float4 sp[NPTS];                     // 64 KB: x, y, z, |p|^2
    __shared__ float          bufd[BUF_ROWS][256];  // 8 KB: scan buffer / publish area
    __shared__ unsigned short bufi[BUF_ROWS][256];  // 4 KB
    __shared__ float gam[H_DIM], bet[H_DIM];        // 1 KB

    const int tid  = threadIdx.x;
    const int lane = tid & 63;
    const int wid  = tid >> 6;                      // 4 waves: candidate-quarter owners
    const int b     = blockIdx.x >> 6;
    const int chunk = blockIdx.x & 63;
    const int q     = chunk * 64 + lane;            // all waves share the same 64 queries

    // ---- stage points: sq matches numpy's ((x*x + y*y) + z*z), per-op rounding ----
    const float* pb = pos + (size_t)b * NPTS * 3;
    for (int j = tid; j < NPTS; j += 256) {
        float x = pb[j * 3 + 0];
        float y = pb[j * 3 + 1];
        float z = pb[j * 3 + 2];
        float sq = __fadd_rn(__fadd_rn(__fmul_rn(x, x), __fmul_rn(y, y)),
                             __fmul_rn(z, z));
        sp[j] = make_float4(x, y, z, sq);
    }

    // ---- FiLM gamma/beta (threads 0..127, one channel each) ----
    if (tid < H_DIM) {
        const float* gl = goal + b * G_DIM;
        float sg = bg[tid];
        float sb = bb[tid];
        #pragma unroll
        for (int g = 0; g < G_DIM; ++g) {
            float gv = gl[g];
            sg = fmaf(gv, Wg[g * H_DIM + tid], sg);
            sb = fmaf(gv, Wb[g * H_DIM + tid], sb);
        }
        gam[tid] = sg;
        bet[tid] = sb;
    }
    __syncthreads();                                // B1: sp + film ready

    const float4 me = sp[q];

    // d2 in numpy's exact association: dot=((xx'+yy')+zz'); d2=(sqi+sqj)-2*dot.
#define CAND_D2(c)                                                             \
    __fsub_rn(__fadd_rn(me.w, (c).w),                                          \
              __fmul_rn(2.0f,                                                  \
                        __fadd_rn(__fadd_rn(__fmul_rn(me.x, (c).x),            \
                                            __fmul_rn(me.y, (c).y)),           \
                                  __fmul_rn(me.z, (c).z))))

    u64 best[KNN];
    #pragma unroll
    for (int k = 0; k < KNN; ++k) best[k] = 0xFFFFFFFFFFFFFFFFull;

    const int jbase = wid * QTR;

    // ---- warmup: branchy direct insert seeds the threshold ----
    for (int j = jbase; j < jbase + WARMUP; ++j) {
        float4 c = sp[j];
        float d2 = fmaxf(CAND_D2(c), 0.0f);
        u64 key = ((u64)__float_as_uint(d2) << 32) | (unsigned)j;
        if (key < best[15]) { INSERT_KEY(key); }
    }

    float thr = __uint_as_float((unsigned)(best[15] >> 32));
    int   cnt = 0;

    // ---- buffered main scan over this wave's quarter ----
    for (int j0 = jbase + WARMUP; j0 < jbase + QTR; j0 += GROUP) {
        #pragma unroll
        for (int jj = 0; jj < GROUP; ++jj) {
            const int j = j0 + jj;
            float4 c = sp[j];
            float d2 = fmaxf(CAND_D2(c), 0.0f);
            if (d2 < thr) {                         // cheap predicated append
                bufd[cnt][tid] = d2;
                bufi[cnt][tid] = (unsigned short)j;
                cnt++;
            }
        }
        if (__any(cnt >= FLUSH_AT)) {               // per-wave, uniform branch
            int t = 0;
            while (__any(t < cnt)) {                // t <= 7 always
                float d2 = bufd[t][tid];
                int   jj = bufi[t][tid];
                u64 key = ((u64)__float_as_uint(d2) << 32) | (unsigned)jj;
                if ((t < cnt) && (key < best[15])) { INSERT_KEY(key); }
                t++;
            }
            cnt = 0;
            thr = __uint_as_float((unsigned)(best[15] >> 32));
        }
    }
    // final flush
    {
        int t = 0;
        while (__any(t < cnt)) {
            float d2 = bufd[t][tid];
            int   jj = bufi[t][tid];
            u64 key = ((u64)__float_as_uint(d2) << 32) | (unsigned)jj;
            if ((t < cnt) && (key < best[15])) { INSERT_KEY(key); }
            t++;
        }
    }

    // ---- cross-wave merge: tree (0<-2, 1<-3) then (0<-1), bitonic, all-static ----
    float*          F = &bufd[0][0];                // 2048 floats
    unsigned short* I = &bufi[0][0];                // 2048 ushorts

    __syncthreads();                                // B2: buffers free for publish

    if (wid >= 2) {                                 // waves 2,3 publish lists
        const int off = (wid - 2) * 1024;
        #pragma unroll
        for (int k = 0; k < KNN; ++k) {
            F[off + k * 64 + lane] = __uint_as_float((unsigned)(best[k] >> 32));
            I[off + k * 64 + lane] = (unsigned short)(best[k] & 0xFFFFu);
        }
    }
    __syncthreads();                                // B3

    // MERGE(off): best = sorted smallest-16 of (best ∪ LDS-list at off).
    // Halver lo[i]=min(A[i],B[15-i]) -> bitonic -> merge network gaps 8,4,2,1.
#define MERGE_FROM(off)                                                        \
    { u64 m[16];                                                               \
      _Pragma("unroll")                                                        \
      for (int i = 0; i < 16; ++i) {                                           \
          int kk = 15 - i;                                                     \
          u64 bk = ((u64)__float_as_uint(F[(off) + kk * 64 + lane]) << 32)     \
                 | (u64)I[(off) + kk * 64 + lane];                             \
          m[i] = best[i] < bk ? best[i] : bk;                                  \
      }                                                                        \
      CE(0,8) CE(1,9) CE(2,10) CE(3,11) CE(4,12) CE(5,13) CE(6,14) CE(7,15)    \
      CE(0,4) CE(1,5) CE(2,6) CE(3,7) CE(8,12) CE(9,13) CE(10,14) CE(11,15)    \
      CE(0,2) CE(1,3) CE(4,6) CE(5,7) CE(8,10) CE(9,11) CE(12,14) CE(13,15)    \
      CE(0,1) CE(2,3) CE(4,5) CE(6,7) CE(8,9) CE(10,11) CE(12,13) CE(14,15)    \
      _Pragma("unroll")                                                        \
      for (int i = 0; i < 16; ++i) best[i] = m[i]; }

    if (wid == 0) MERGE_FROM(0);                    // 0 <- 2   (A-list has lower j: ties ok)
    if (wid == 1) MERGE_FROM(1024);                 // 1 <- 3

    if (wid == 1) {                                 // wave 1 publishes its merged list
        #pragma unroll
        for (int k = 0; k < KNN; ++k) {
            F[1024 + k * 64 + lane] = __uint_as_float((unsigned)(best[k] >> 32));
            I[1024 + k * 64 + lane] = (unsigned short)(best[k] & 0xFFFFu);
        }
    }
    __syncthreads();                                // B4 (last barrier: all threads)

    if (wid != 0) return;                           // wave 0 finishes

    MERGE_FROM(1024);                               // 0 <- 1 : final global top-16

    // ---- neighbor mean offset (ascending-(d2,idx) order == reference) ----
    float sx = 0.0f, sy = 0.0f, sz = 0.0f;
    #pragma unroll
    for (int k = 0; k < KNN; ++k) {
        float4 nb = sp[(unsigned)(best[k] & 0xFFFFu)];
        sx += nb.x; sy += nb.y; sz += nb.z;
    }
    const float inv = 1.0f / (float)KNN;
    const float lx = sx * inv - me.x;
    const float ly = sy * inv - me.y;
    const float lz = sz * inv - me.z;

    // ---- MLP: h = relu([pos, ctx] @ W1 + b1) ----
    const float x0 = me.x, x1 = me.y, x2 = me.z, x3 = lx, x4 = ly, x5 = lz;
    float h[HID1];
    #pragma unroll
    for (int c = 0; c < HID1; ++c) {
        float a = b1[c];
        a = fmaf(x0, W1[0 * HID1 + c], a);
        a = fmaf(x1, W1[1 * HID1 + c], a);
        a = fmaf(x2, W1[2 * HID1 + c], a);
        a = fmaf(x3, W1[3 * HID1 + c], a);
        a = fmaf(x4, W1[4 * HID1 + c], a);
        a = fmaf(x5, W1[5 * HID1 + c], a);
        h[c] = fmaxf(a, 0.0f);
    }

    // ---- stream hidden-128 through FiLM into the 32-wide affordance acc ----
    float acc[A_DIM];
    #pragma unroll
    for (int a = 0; a < A_DIM; ++a) acc[a] = ba[a];

    for (int c = 0; c < H_DIM; ++c) {
        float s = b2[c];
        #pragma unroll
        for (int k = 0; k < HID1; ++k) s = fmaf(h[k], W2[k * H_DIM + c], s);
        float f = fmaxf(s, 0.0f);
        f = fmaf(gam[c], f, bet[c]);
        const float* wac = Wa + c * A_DIM;
        #pragma unroll
        for (int a = 0; a < A_DIM; ++a) acc[a] = fmaf(f, wac[a], acc[a]);
    }

    // ---- relu + float4 stores ----
    float4* op4 = (float4*)(out + ((size_t)b * NPTS + q) * A_DIM);
    #pragma unroll
    for (int v = 0; v < A_DIM / 4; ++v) {
        float4 o;
        o.x = fmaxf(acc[v * 4 + 0], 0.0f);
        o.y = fmaxf(acc[v * 4 + 1], 0.0f);
        o.z = fmaxf(acc[v * 4 + 2], 0.0f);
        o.w = fmaxf(acc[v * 4 + 3], 0.0f);
        op4[v] = o;
    }
#undef CAND_D2
}

extern "C" void kernel_launch(void* const* d_in, const int* in_sizes, int n_in,
                              void* d_out, int out_size, void* d_ws, size_t ws_size,
                              hipStream_t stream) {
    const float* pos  = (const float*)d_in[0];
    const float* goal = (const float*)d_in[1];
    const float* W1   = (const float*)d_in[2];
    const float* b1   = (const float*)d_in[3];
    const float* W2   = (const float*)d_in[4];
    const float* b2   = (const float*)d_in[5];
    const float* Wg   = (const float*)d_in[6];
    const float* bg   = (const float*)d_in[7];
    const float* Wb   = (const float*)d_in[8];
    const float* bb   = (const float*)d_in[9];
    const float* Wa   = (const float*)d_in[10];
    const float* ba   = (const float*)d_in[11];
    float* out = (float*)d_out;

    const int B = in_sizes[0] / (NPTS * 3);
    dim3 grid(B * 64);
    dim3 block(256);
    hipLaunchKernelGGL(knn_film_mlp_kernel, grid, block, 0, stream,
                       pos, goal, W1, b1, W2, b2, Wg, bg, Wb, bb, Wa, ba, out);
}

// Round 6
// 262.686 us; speedup vs baseline: 3.6293x; 1.4161x over previous
//
#include <hip/hip_runtime.h>
#include <math.h>

#define NPTS 4096
#define QTR  1024
#define KNN  16
#define H_DIM 128
#define HID1 64
#define A_DIM 32
#define G_DIM 16

#define BUF_ROWS 16
#define FLUSH_AT 8
#define GROUP 8
#define EPS 3e-4f        // covers |fma-surrogate - exact-rn d2| (~5e-5) with 6x margin

typedef unsigned long long u64;

// key = (f32 bits of d2) << 32 | j.  d2 >= 0 -> u64 ascending == (d2 asc, j asc)
// == jax.lax.top_k's stable lowest-index-tie-break order.

#define SWAP_ST(k)                                                         \
    { bool sw_ = best[k] < best[k-1];                                      \
      u64 lo_ = sw_ ? best[k] : best[k-1];                                 \
      u64 hi_ = sw_ ? best[k-1] : best[k];                                 \
      best[k-1] = lo_; best[k] = hi_; }

#define INSERT_KEY(keyv)                                                   \
    { best[15] = (keyv);                                                   \
      SWAP_ST(15) SWAP_ST(14) SWAP_ST(13) SWAP_ST(12) SWAP_ST(11)          \
      SWAP_ST(10) SWAP_ST(9)  SWAP_ST(8)  SWAP_ST(7)  SWAP_ST(6)           \
      SWAP_ST(5)  SWAP_ST(4)  SWAP_ST(3)  SWAP_ST(2)  SWAP_ST(1) }

#define CE(i, j)                                                           \
    { u64 x_ = m[i], y_ = m[j];                                            \
      bool sw_ = y_ < x_;                                                  \
      m[i] = sw_ ? y_ : x_; m[j] = sw_ ? x_ : y_; }

__global__ __launch_bounds__(256, 2) void knn_film_mlp_kernel(
    const float* __restrict__ pos, const float* __restrict__ goal,
    const float* __restrict__ W1, const float* __restrict__ b1,
    const float* __restrict__ W2, const float* __restrict__ b2,
    const float* __restrict__ Wg, const float* __restrict__ bg,
    const float* __restrict__ Wb, const float* __restrict__ bb,
    const float* __restrict__ Wa, const float* __restrict__ ba,
    float* __restrict__ out)
{
    __shared__ float4 sp[NPTS];                     // 64 KB; reused as MLP partials
    __shared__ unsigned short bufi[BUF_ROWS][256];  // 8 KB; reused as pub-d2 (f32 view)
    __shared__ unsigned short pubi[2][KNN][64];     // 4 KB
    __shared__ float gam[H_DIM], bet[H_DIM];        // 1 KB
    __shared__ float4 lc[64];                       // 1 KB local context

    const int tid  = threadIdx.x;
    const int lane = tid & 63;
    const int wid  = tid >> 6;                      // 4 waves own candidate quarters
    const int b     = blockIdx.x >> 6;
    const int chunk = blockIdx.x & 63;
    const int q     = chunk * 64 + lane;

    // ---- stage points: sq = ((x*x + y*y) + z*z), per-op rounding == numpy ----
    const float* pb = pos + (size_t)b * NPTS * 3;
    for (int j = tid; j < NPTS; j += 256) {
        float x = pb[j * 3 + 0];
        float y = pb[j * 3 + 1];
        float z = pb[j * 3 + 2];
        float sq = __fadd_rn(__fadd_rn(__fmul_rn(x, x), __fmul_rn(y, y)),
                             __fmul_rn(z, z));
        sp[j] = make_float4(x, y, z, sq);
    }
    if (tid < H_DIM) {
        const float* gl = goal + b * G_DIM;
        float sg = bg[tid];
        float sb = bb[tid];
        #pragma unroll
        for (int g = 0; g < G_DIM; ++g) {
            float gv = gl[g];
            sg = fmaf(gv, Wg[g * H_DIM + tid], sg);
            sb = fmaf(gv, Wb[g * H_DIM + tid], sb);
        }
        gam[tid] = sg;
        bet[tid] = sb;
    }
    __syncthreads();                                // B1

    const float4 me = sp[q];
    const float nx = -2.0f * me.x, ny = -2.0f * me.y, nz = -2.0f * me.z;

    // exact d2, numpy association: ((xx'+yy')+zz'); (sqi+sqj)-2*dot; one final rounding
#define CAND_D2(c)                                                             \
    __fsub_rn(__fadd_rn(me.w, (c).w),                                          \
              __fmul_rn(2.0f,                                                  \
                        __fadd_rn(__fadd_rn(__fmul_rn(me.x, (c).x),            \
                                            __fmul_rn(me.y, (c).y)),           \
                                  __fmul_rn(me.z, (c).z))))

    u64 best[KNN];
    #pragma unroll
    for (int k = 0; k < KNN; ++k) best[k] = 0xFFFFFFFFFFFFFFFFull;

    const int jbase = wid * QTR;

    // ---- warmup: 16 unconditional exact inserts seed the threshold ----
    for (int j = jbase; j < jbase + KNN; ++j) {
        float4 c = sp[j];
        float d2 = fmaxf(CAND_D2(c), 0.0f);
        u64 key = ((u64)__float_as_uint(d2) << 32) | (unsigned)j;
        INSERT_KEY(key);
    }
    float thrm = (__uint_as_float((unsigned)(best[15] >> 32)) - me.w) + EPS;
    int cnt = 0;

    // FLUSH: exact-recheck buffered j's (gather sp[j], exact d2, u64 insert)
#define FLUSH()                                                                \
    { int t = 0;                                                               \
      while (__any(t < cnt)) {                                                 \
          int j = bufi[t][tid] & (NPTS - 1);                                   \
          float4 c = sp[j];                                                    \
          float d2 = fmaxf(CAND_D2(c), 0.0f);                                  \
          u64 key = ((u64)__float_as_uint(d2) << 32) | (unsigned)j;            \
          if ((t < cnt) && (key < best[15])) { INSERT_KEY(key); }              \
          t++;                                                                 \
      }                                                                        \
      cnt = 0;                                                                 \
      thrm = (__uint_as_float((unsigned)(best[15] >> 32)) - me.w) + EPS; }

    // ---- main scan: 4-op branchless surrogate filter + lean append ----
    for (int j0 = jbase + KNN; j0 < jbase + QTR; j0 += GROUP) {
        #pragma unroll
        for (int jj = 0; jj < GROUP; ++jj) {
            const int j = j0 + jj;
            float4 c = sp[j];
            float s = fmaf(nx, c.x, fmaf(ny, c.y, fmaf(nz, c.z, c.w)));
            bool pass = s < thrm;               // no false negatives (EPS bound)
            bufi[cnt][tid] = (unsigned short)j; // unconditional; row cnt is free
            cnt += pass ? 1 : 0;
        }
        if (__any(cnt >= FLUSH_AT)) FLUSH();    // cnt <= 7+8=15 < BUF_ROWS
    }
    FLUSH();                                    // final drain

    // ---- cross-wave merge tree: (0<-2, 1<-3) then (0<-1); all-static ----
    float* pubd = (float*)&bufi[0][0];          // 2 lists x [16][64] f32 = 8 KB

#define PUBLISH(l)                                                             \
    _Pragma("unroll")                                                          \
    for (int k = 0; k < KNN; ++k) {                                            \
        pubd[(l) * 1024 + k * 64 + lane] =                                     \
            __uint_as_float((unsigned)(best[k] >> 32));                        \
        pubi[l][k][lane] = (unsigned short)(best[k] & 0xFFFFu);                \
    }

    // merge sorted best[16] with published sorted list l -> smallest 16, sorted
#define MERGE_FROM(l)                                                          \
    { u64 m[16];                                                               \
      _Pragma("unroll")                                                        \
      for (int i = 0; i < 16; ++i) {                                           \
          int kk = 15 - i;                                                     \
          u64 bk = ((u64)__float_as_uint(pubd[(l) * 1024 + kk * 64 + lane])    \
                    << 32) | (u64)pubi[l][kk][lane];                           \
          m[i] = best[i] < bk ? best[i] : bk;                                  \
      }                                                                        \
      CE(0,8) CE(1,9) CE(2,10) CE(3,11) CE(4,12) CE(5,13) CE(6,14) CE(7,15)    \
      CE(0,4) CE(1,5) CE(2,6) CE(3,7) CE(8,12) CE(9,13) CE(10,14) CE(11,15)    \
      CE(0,2) CE(1,3) CE(4,6) CE(5,7) CE(8,10) CE(9,11) CE(12,14) CE(13,15)    \
      CE(0,1) CE(2,3) CE(4,5) CE(6,7) CE(8,9) CE(10,11) CE(12,13) CE(14,15)    \
      _Pragma("unroll")                                                        \
      for (int i = 0; i < 16; ++i) best[i] = m[i]; }

    __syncthreads();                            // B2: scan buffers free
    if (wid >= 2) PUBLISH(wid - 2);
    __syncthreads();                            // B3
    if (wid == 0) MERGE_FROM(0);
    if (wid == 1) { MERGE_FROM(1); PUBLISH(1); }
    __syncthreads();                            // B4
    if (wid == 0) {
        MERGE_FROM(1);                          // final global top-16, sorted
        // neighbor mean offset in ascending-(d2,idx) order == reference
        float sx = 0.0f, sy = 0.0f, sz = 0.0f;
        #pragma unroll
        for (int k = 0; k < KNN; ++k) {
            float4 nb = sp[(unsigned)(best[k] & 0xFFFFu)];
            sx += nb.x; sy += nb.y; sz += nb.z;
        }
        const float inv = 1.0f / (float)KNN;
        lc[lane] = make_float4(sx * inv - me.x, sy * inv - me.y,
                               sz * inv - me.z, 0.0f);
    }
    __syncthreads();                            // B5: lc ready; sp dead -> partials

    // ---- MLP, all 4 waves: wave ci handles channels [ci*32, ci*32+32) ----
    {
        float4 l4 = lc[lane];
        const float x3 = l4.x, x4 = l4.y, x5 = l4.z;
        float h[HID1];
        #pragma unroll
        for (int c = 0; c < HID1; ++c) {
            float a = b1[c];
            a = fmaf(me.x, W1[0 * HID1 + c], a);
            a = fmaf(me.y, W1[1 * HID1 + c], a);
            a = fmaf(me.z, W1[2 * HID1 + c], a);
            a = fmaf(x3,   W1[3 * HID1 + c], a);
            a = fmaf(x4,   W1[4 * HID1 + c], a);
            a = fmaf(x5,   W1[5 * HID1 + c], a);
            h[c] = fmaxf(a, 0.0f);
        }
        float acc[A_DIM];
        #pragma unroll
        for (int a = 0; a < A_DIM; ++a) acc[a] = 0.0f;
        const int ci = wid;                     // uniform per wave
        #pragma unroll 4
        for (int cc = 0; cc < 32; ++cc) {
            const int c = ci * 32 + cc;
            float s = b2[c];
            #pragma unroll
            for (int k = 0; k < HID1; ++k) s = fmaf(h[k], W2[k * H_DIM + c], s);
            float f = fmaf(gam[c], fmaxf(s, 0.0f), bet[c]);
            const float* wac = Wa + c * A_DIM;
            #pragma unroll
            for (int a = 0; a < A_DIM; ++a) acc[a] = fmaf(f, wac[a], acc[a]);
        }
        // column-layout partials in sp: P[(ci*32 + a)*64 + lane] (conflict-free)
        float* P = (float*)sp;
        #pragma unroll
        for (int a = 0; a < A_DIM; ++a) P[(ci * A_DIM + a) * 64 + lane] = acc[a];
    }
    __syncthreads();                            // B6

    // ---- reduce partials + bias + relu; coalesced float4 stores ----
    {
        const float* P = (const float*)sp;
        const int qi = tid >> 2, a0 = (tid & 3) * 8;
        float o[8];
        #pragma unroll
        for (int a = 0; a < 8; ++a) {
            float ssum = ba[a0 + a];
            #pragma unroll
            for (int c4 = 0; c4 < 4; ++c4)
                ssum += P[(c4 * A_DIM + a0 + a) * 64 + qi];
            o[a] = fmaxf(ssum, 0.0f);
        }
        float4* op4 = (float4*)(out + ((size_t)b * NPTS + chunk * 64 + qi) * A_DIM + a0);
        op4[0] = make_float4(o[0], o[1], o[2], o[3]);
        op4[1] = make_float4(o[4], o[5], o[6], o[7]);
    }
#undef CAND_D2
#undef FLUSH
#undef PUBLISH
#undef MERGE_FROM
}

extern "C" void kernel_launch(void* const* d_in, const int* in_sizes, int n_in,
                              void* d_out, int out_size, void* d_ws, size_t ws_size,
                              hipStream_t stream) {
    const float* pos  = (const float*)d_in[0];
    const float* goal = (const float*)d_in[1];
    const float* W1   = (const float*)d_in[2];
    const float* b1   = (const float*)d_in[3];
    const float* W2   = (const float*)d_in[4];
    const float* b2   = (const float*)d_in[5];
    const float* Wg   = (const float*)d_in[6];
    const float* bg   = (const float*)d_in[7];
    const float* Wb   = (const float*)d_in[8];
    const float* bb   = (const float*)d_in[9];
    const float* Wa   = (const float*)d_in[10];
    const float* ba   = (const float*)d_in[11];
    float* out = (float*)d_out;

    const int B = in_sizes[0] / (NPTS * 3);
    dim3 grid(B * 64);
    dim3 block(256);
    hipLaunchKernelGGL(knn_film_mlp_kernel, grid, block, 0, stream,
                       pos, goal, W1, b1, W2, b2, Wg, bg, Wb, bb, Wa, ba, out);
}